// Round 6
// baseline (20.576 us; speedup 1.0000x reference)
//
#include <hip/hip_runtime.h>

// EctTransform: out[b,r,t] = (sum_n sigmoid(100*(lin_r - x[b,n,:].v[:,t]))) / max_{r,t}
// B=16, N=2048, D=3, R=64, T=64.
//
// Round 17: SCALARIZATION A/B. Identical geometry/staging/reduce/unroll to
// r16 (512 blocks x 512 thr, 2/CU, WPTS=64, unroll 2); the v2f packed math
// is mechanically scalarized to per-component float ops (same ops, same
// order, fma-for-fma -> bit-identical absmax). Rationale: MI355X fp32 peak
// (157.3 TF) implies v_pk_*_f32 has NO flops bonus over scalar: pk is
// either 4 cyc/wave64 (neutral) or 8 cyc (two passes = HALF the rate of
// the scalar pair). All stall theories (occupancy x2, I$) are falsified;
// pk-rate is the last untested load-bearing assumption and exactly the
// size of the measured-vs-floor gap (partial ~16us vs ~8-9us model).
// asm SSA pins on dot results and t-values block SLP re-packing to VOP3P.
//   pk@4 -> dur ~18.4-19.2 (neutral, buys the ISA bit)
//   pk@8 -> dur ~14.5-15.5 (partial -25-30%)
// Grid: 16b x 8rg x 4s = 512 blocks x 512 thr (8 waves x 64 pts) = 2/CU.

#define BATCH  16
#define NPTS   2048
#define RES    64
#define NT     64
#define RPER   8
#define NSPLIT 4
#define NWAVES 8
#define WPTS   64                       // points per wave
#define BPTS   512                      // points per block
#define HPTS   256                      // even/odd halves per block
#define CLAMP30 1073741824.0f           // 2^30

typedef float v2f __attribute__((ext_vector_type(2)));

__device__ __forceinline__ float fexp2(float x) { return __builtin_amdgcn_exp2f(x); }
__device__ __forceinline__ float frcp(float x)  { return __builtin_amdgcn_rcpf(x); }
#define PIN(v) asm volatile("" : "+v"(v))

__global__ __launch_bounds__(512, 4)
void ect_partial_kernel(const float* __restrict__ x, const float* __restrict__ v,
                        float* __restrict__ part) {
    const int tid  = threadIdx.x;
    const int lane = tid & 63;          // t
    const int w    = tid >> 6;          // wave (8 per block)
    const int bid  = blockIdx.x;
    const int s    = bid & 3;           // n-chunk of 512
    const int rg   = (bid >> 2) & 7;    // r-group of 8
    const int b    = bid >> 5;

    __shared__ float xe[HPTS], ye[HPTS], ze[HPTS];   // even points (SoA)
    __shared__ float xo[HPTS], yo[HPTS], zo[HPTS];   // odd points
    __shared__ float red[NWAVES][RPER * 64];         // 16 KB

    {   // all 512 threads stage one point each
        const float* xb = x + ((size_t)b * NPTS + (size_t)s * BPTS + tid) * 3;
        const float x0 = xb[0], y0 = xb[1], z0 = xb[2];
        const int h = tid >> 1;
        if (tid & 1) { xo[h] = x0; yo[h] = y0; zo[h] = z0; }
        else         { xe[h] = x0; ye[h] = y0; ze[h] = z0; }
    }

    const float K    = 144.26950408889634f;   // 100 * log2(e)
    const float step = 2.0f / 63.0f;
    const float Ks   = K * step;              // 4.58 per r-step

    const float msv0 = K * v[0 * NT + lane];
    const float msv1 = K * v[1 * NT + lane];
    const float msv2 = K * v[2 * NT + lane];
    const float mslin = -K * (-1.0f + step * (float)(rg * RPER));

    const float c1 = fexp2(-Ks);
    const float c2 = c1 * c1, c3 = c2 * c1, c4 = c3 * c1, c6 = c4 * c2;
    const float Cs[4]  = {1.0f, c1, c2, c3};
    const float C2s[4] = {1.0f, c2, c4, c6};

    __syncthreads();

    float acc[2][4][2];
#pragma unroll
    for (int g = 0; g < 2; ++g)
#pragma unroll
        for (int j = 0; j < 4; ++j) { acc[g][j][0] = 0.0f; acc[g][j][1] = 0.0f; }

#pragma unroll 2
    for (int it = 0; it < WPTS / 8; ++it) {
        const int base = w * (WPTS / 2) + it * 4;     // pair index, wave-uniform
        // vector LDS loads (ds_read_b64), then scalar component extraction
        const v2f xe0 = *(const v2f*)&xe[base],  xe1 = *(const v2f*)&xe[base + 2];
        const v2f ye0 = *(const v2f*)&ye[base],  ye1 = *(const v2f*)&ye[base + 2];
        const v2f ze0 = *(const v2f*)&ze[base],  ze1 = *(const v2f*)&ze[base + 2];
        const v2f xo0 = *(const v2f*)&xo[base],  xo1 = *(const v2f*)&xo[base + 2];
        const v2f yo0 = *(const v2f*)&yo[base],  yo1 = *(const v2f*)&yo[base + 2];
        const v2f zo0 = *(const v2f*)&zo[base],  zo1 = *(const v2f*)&zo[base + 2];

        const float pxE[4] = {xe0.x, xe0.y, xe1.x, xe1.y};
        const float pyE[4] = {ye0.x, ye0.y, ye1.x, ye1.y};
        const float pzE[4] = {ze0.x, ze0.y, ze1.x, ze1.y};
        const float pxO[4] = {xo0.x, xo0.y, xo1.x, xo1.y};
        const float pyO[4] = {yo0.x, yo0.y, yo1.x, yo1.y};
        const float pzO[4] = {zo0.x, zo0.y, zo1.x, zo1.y};

        // per-point scalar dots + clamp + exp + group bases
        float S[2][4], P[2][4];
#pragma unroll
        for (int k = 0; k < 4; ++k) {
            float mE = __builtin_fmaf(pzE[k], msv2,
                        __builtin_fmaf(pyE[k], msv1,
                         __builtin_fmaf(pxE[k], msv0, mslin)));
            float mO = __builtin_fmaf(pzO[k], msv2,
                        __builtin_fmaf(pyO[k], msv1,
                         __builtin_fmaf(pxO[k], msv0, mslin)));
            PIN(mE); PIN(mO);                         // block SLP re-packing
            mE = fminf(mE, 48.0f);
            mO = fminf(mO, 48.0f);
            const float uE = fexp2(mE), uO = fexp2(mO);
            const float g0E = fminf(uE, CLAMP30), g0O = fminf(uO, CLAMP30);
            const float g1E = uE * c4,            g1O = uO * c4;
            S[0][k] = g0E + g0O;  P[0][k] = g0E * g0O;
            S[1][k] = g1E + g1O;  P[1][k] = g1E * g1O;
        }

        // merged fractions: half h merges pair h with pair h+2 (== v2f comp h)
#pragma unroll
        for (int g = 0; g < 2; ++g) {
#pragma unroll
            for (int j = 0; j < 4; ++j) {
#pragma unroll
                for (int h = 0; h < 2; ++h) {
                    float tA = __builtin_fmaf(S[g][h],     Cs[j], 1.0f);
                    float tB = __builtin_fmaf(S[g][h + 2], Cs[j], 1.0f);
                    PIN(tA); PIN(tB);                 // block SLP re-packing
                    const float dA = __builtin_fmaf(P[g][h],     C2s[j], tA);
                    const float dB = __builtin_fmaf(P[g][h + 2], C2s[j], tB);
                    const float ds  = dA + dB;
                    const float num = __builtin_fmaf(tA, dB,
                                       __builtin_fmaf(tB, dA, ds));
                    const float den = dA * dB;
                    const float R   = frcp(den);
                    acc[g][j][h] = __builtin_fmaf(num, R, acc[g][j][h]);
                }
            }
        }
    }

    // block reduce over the 8 waves -> partial [8r][64t]
#pragma unroll
    for (int g = 0; g < 2; ++g)
#pragma unroll
        for (int j = 0; j < 4; ++j)
            red[w][(g * 4 + j) * 64 + lane] = acc[g][j][0] + acc[g][j][1];
    __syncthreads();

    {   // all 512 threads: one output cell each
        float sum = 0.0f;
#pragma unroll
        for (int q = 0; q < NWAVES; ++q) sum += red[q][tid];
        part[((size_t)(b * NSPLIT + s)) * (RES * NT) + rg * 512 + tid] = sum;
    }
}

__global__ __launch_bounds__(1024, 2)
void ect_norm_kernel(const float* __restrict__ part, float* __restrict__ out) {
    const int b   = blockIdx.x;
    const int tid = threadIdx.x;               // one float4 cell per thread (1024 cells)

    const float4* pb = (const float4*)(part + (size_t)b * NSPLIT * (RES * NT));
    float4 s4 = pb[tid];
#pragma unroll
    for (int c = 1; c < NSPLIT; ++c) {
        const float4 q4 = pb[c * 1024 + tid];
        s4.x += q4.x; s4.y += q4.y; s4.z += q4.z; s4.w += q4.w;
    }

    float m = fmaxf(fmaxf(s4.x, s4.y), fmaxf(s4.z, s4.w));
#pragma unroll
    for (int off = 32; off >= 1; off >>= 1)
        m = fmaxf(m, __shfl_xor(m, off, 64));

    __shared__ float sm[16];
    if ((tid & 63) == 0) sm[tid >> 6] = m;
    __syncthreads();
    float g = sm[0];
#pragma unroll
    for (int i = 1; i < 16; ++i) g = fmaxf(g, sm[i]);

    const float rinv = frcp(g);
    float4 o;
    o.x = s4.x * rinv; o.y = s4.y * rinv; o.z = s4.z * rinv; o.w = s4.w * rinv;
    ((float4*)(out + (size_t)b * (RES * NT)))[tid] = o;
}

extern "C" void kernel_launch(void* const* d_in, const int* in_sizes, int n_in,
                              void* d_out, int out_size, void* d_ws, size_t ws_size,
                              hipStream_t stream) {
    const float* x = (const float*)d_in[0];   // (16, 2048, 3)
    const float* v = (const float*)d_in[1];   // (3, 64)
    float* out  = (float*)d_out;              // (16, 64, 64)
    float* part = (float*)d_ws;               // [16][4][4096] f32 = 1 MB

    ect_partial_kernel<<<BATCH * RPER * NSPLIT, 512, 0, stream>>>(x, v, part);
    ect_norm_kernel<<<BATCH, 1024, 0, stream>>>(part, out);
}